// Round 6
// baseline (214.482 us; speedup 1.0000x reference)
//
#include <hip/hip_runtime.h>
#include <math.h>

#define NTOK 8192
#define SD   4096
#define ITERS 20

typedef __attribute__((ext_vector_type(8))) short short8;
typedef __attribute__((ext_vector_type(8))) unsigned short ushort8;
typedef __attribute__((ext_vector_type(4))) unsigned short us4;
typedef __attribute__((ext_vector_type(4))) float f32x4;

__device__ inline unsigned short f2bf(float x) {
    unsigned int u = __float_as_uint(x);
    unsigned int r = (u + 0x7FFFu + ((u >> 16) & 1u)) >> 16;
    return (unsigned short)r;
}
__device__ inline float bf2f(unsigned short u) {
    return __uint_as_float((unsigned int)u << 16);
}

// ---------------- Kernel P: cgT[d][k] = bf16(compress[k][d] * (gamma[k]+1)) ----------------
__global__ __launch_bounds__(256) void k_prep(const float* __restrict__ compress,
                                              const float* __restrict__ gamma,
                                              unsigned short* __restrict__ cgT)
{
    __shared__ float tb[64][65];
    __shared__ float gsh[64];
    const int tid = threadIdx.x;
    const int k0 = blockIdx.x * 64;
    #pragma unroll 4
    for (int q = 0; q < 16; ++q) {
        const int idx = q * 256 + tid;
        const int r = idx >> 6, dd = idx & 63;
        tb[r][dd] = compress[(size_t)(k0 + r) * 64 + dd];
    }
    if (tid < 64) gsh[tid] = gamma[k0 + tid] + 1.0f;
    __syncthreads();
    #pragma unroll 4
    for (int q = 0; q < 16; ++q) {
        const int idx = q * 256 + tid;
        const int d = idx >> 6, r = idx & 63;
        cgT[(size_t)d * SD + k0 + r] = f2bf(tb[r][d] * gsh[r]);
    }
}

// ---------------- Kernel PT: tlcatT[n][k] = bf16(tl_cat[k][n]), n in [0,640) ----------------
__global__ __launch_bounds__(256) void k_prept(const float* __restrict__ tl_pre,
                                               const float* __restrict__ tl_al,
                                               const float* __restrict__ tl_nx,
                                               const float* __restrict__ tl_po,
                                               unsigned short* __restrict__ tlT)
{
    const int idx = blockIdx.x * 256 + threadIdx.x;
    if (idx >= 640 * 64) return;
    const int k = idx / 640, n = idx - k * 640;
    float v;
    if (n < 64)       v = tl_pre[k * 64 + n];
    else if (n < 320) v = tl_al[k * 256 + (n - 64)];
    else if (n < 576) v = tl_nx[k * 256 + (n - 320)];
    else              v = tl_po[k * 64 + (n - 576)];
    tlT[(size_t)n * 64 + k] = f2bf(v);
}

// ---------------- Kernel W: transpose + convert W -> WT bf16 [n][k] ----------------
__global__ __launch_bounds__(256) void k_wt(const float* __restrict__ W,
                                            unsigned short* __restrict__ WT)
{
    __shared__ float tb[64][65];
    const int k0 = blockIdx.y * 64, n0 = blockIdx.x * 64;
    #pragma unroll 4
    for (int q = 0; q < 16; ++q) {
        const int idx = q * 256 + threadIdx.x;
        const int r = idx >> 6, c = idx & 63;
        tb[r][c] = W[(size_t)(k0 + r) * 1024 + n0 + c];
    }
    __syncthreads();
    #pragma unroll 4
    for (int q = 0; q < 16; ++q) {
        const int idx = q * 256 + threadIdx.x;
        const int n = idx >> 6, k = idx & 63;
        WT[(size_t)(n0 + n) * 1024 + k0 + k] = f2bf(tb[k][n]);
    }
}

// ---------------- Kernel A: codeBF = bf16(scale * (s @ cg)) via MFMA; also emits s_bf ----------------
// 512 blocks x 16 tokens (2 blocks/CU). Wave w handles interleaved K-slices [ks*128+w*32, +32).
__global__ __launch_bounds__(256) void k_code4(const float* __restrict__ s,
                                               const unsigned short* __restrict__ cgT,
                                               unsigned short* __restrict__ codeBF,
                                               unsigned short* __restrict__ s_bf)
{
    __shared__ __align__(16) unsigned short s_sh[16 * 152];
    __shared__ __align__(16) unsigned short cg_sh[64 * 152];
    __shared__ float red[4 * 16 * 68];
    __shared__ float ssq_sh[16];
    const int tid  = threadIdx.x;
    const int lane = tid & 63;
    const int wid  = tid >> 6;
    const int tok0 = blockIdx.x * 16;
    const int st_tok = tid >> 4;        // 16 threads per token
    const int st_k   = (tid & 15) * 8;  // 8 f32 each
    const int sg_d   = tid >> 2;
    const int sg_k   = (tid & 3) * 32;
    const int wk = wid * 32;

    float ssq = 0.f;
    f32x4 acc[4];
    #pragma unroll
    for (int ni = 0; ni < 4; ++ni) acc[ni] = (f32x4){0.f, 0.f, 0.f, 0.f};

    for (int ks = 0; ks < 32; ++ks) {
        const int kg = ks * 128;
        __syncthreads();  // WAR guard
        {
            const float4* sp = (const float4*)(s + (size_t)(tok0 + st_tok) * SD + kg + st_k);
            float4 v0 = sp[0], v1 = sp[1];
            ssq += v0.x*v0.x + v0.y*v0.y + v0.z*v0.z + v0.w*v0.w
                 + v1.x*v1.x + v1.y*v1.y + v1.z*v1.z + v1.w*v1.w;
            ushort8 pk;
            pk[0]=f2bf(v0.x); pk[1]=f2bf(v0.y); pk[2]=f2bf(v0.z); pk[3]=f2bf(v0.w);
            pk[4]=f2bf(v1.x); pk[5]=f2bf(v1.y); pk[6]=f2bf(v1.z); pk[7]=f2bf(v1.w);
            *(ushort8*)(s_sh + st_tok * 152 + st_k) = pk;
            if (s_bf)
                *(ushort8*)(s_bf + (size_t)(tok0 + st_tok) * SD + kg + st_k) = pk;
        }
        {
            const ushort8* gp = (const ushort8*)(cgT + (size_t)sg_d * SD + kg + sg_k);
            ushort8 c0 = gp[0], c1 = gp[1], c2 = gp[2], c3 = gp[3];
            ushort8* cw = (ushort8*)(cg_sh + sg_d * 152 + sg_k);
            cw[0] = c0; cw[1] = c1; cw[2] = c2; cw[3] = c3;
        }
        __syncthreads();

        short8 a = *(const short8*)(s_sh + (lane & 15) * 152 + wk + (lane >> 4) * 8);
        short8 b[4];
        #pragma unroll
        for (int ni = 0; ni < 4; ++ni)
            b[ni] = *(const short8*)(cg_sh + (ni * 16 + (lane & 15)) * 152 + wk + (lane >> 4) * 8);
        #pragma unroll
        for (int ni = 0; ni < 4; ++ni)
            acc[ni] = __builtin_amdgcn_mfma_f32_16x16x32_bf16(a, b[ni], acc[ni], 0, 0, 0);
    }

    // ssq: reduce across the 16 threads sharing a token
    ssq += __shfl_xor(ssq, 1);
    ssq += __shfl_xor(ssq, 2);
    ssq += __shfl_xor(ssq, 4);
    ssq += __shfl_xor(ssq, 8);
    if ((tid & 15) == 0) ssq_sh[st_tok] = ssq;

    // per-wave partials: C/D layout col=lane&15 (d), row=(lane>>4)*4+r (token)
    #pragma unroll
    for (int ni = 0; ni < 4; ++ni)
        #pragma unroll
        for (int r = 0; r < 4; ++r)
            red[wid * 1088 + ((lane >> 4) * 4 + r) * 68 + ni * 16 + (lane & 15)] = acc[ni][r];
    __syncthreads();
    if (tid < 16) ssq_sh[tid] = 64.0f / fmaxf(sqrtf(ssq_sh[tid]), 1e-12f);
    __syncthreads();

    #pragma unroll
    for (int q = 0; q < 4; ++q) {
        const int idx = q * 256 + tid;
        const int tok = idx >> 6, d = idx & 63;
        float v = red[0 * 1088 + tok * 68 + d] + red[1 * 1088 + tok * 68 + d]
                + red[2 * 1088 + tok * 68 + d] + red[3 * 1088 + tok * 68 + d];
        codeBF[(size_t)(tok0 + tok) * 64 + d] = f2bf(v * ssq_sh[tok]);
    }
}

// ---------------- Kernel L: logits_all[8192][640] = codeBF @ tlT^T ----------------
__global__ __launch_bounds__(256) void k_logits(const unsigned short* __restrict__ codeBF,
                                                const unsigned short* __restrict__ tlT,
                                                float* __restrict__ logits)
{
    const int tid  = threadIdx.x;
    const int lane = tid & 63;
    const int wid  = tid >> 6;
    const int m0 = blockIdx.y * 64 + wid * 16;
    const int n0 = blockIdx.x * 128;

    f32x4 acc[8];
    #pragma unroll
    for (int ni = 0; ni < 8; ++ni) acc[ni] = (f32x4){0.f, 0.f, 0.f, 0.f};

    #pragma unroll
    for (int ks = 0; ks < 2; ++ks) {
        const int ko = ks * 32 + (lane >> 4) * 8;
        short8 a = *(const short8*)(codeBF + (size_t)(m0 + (lane & 15)) * 64 + ko);
        short8 b[8];
        #pragma unroll
        for (int ni = 0; ni < 8; ++ni)
            b[ni] = *(const short8*)(tlT + (size_t)(n0 + ni * 16 + (lane & 15)) * 64 + ko);
        #pragma unroll
        for (int ni = 0; ni < 8; ++ni)
            acc[ni] = __builtin_amdgcn_mfma_f32_16x16x32_bf16(a, b[ni], acc[ni], 0, 0, 0);
    }
    #pragma unroll
    for (int ni = 0; ni < 8; ++ni)
        #pragma unroll
        for (int r = 0; r < 4; ++r)
            logits[(size_t)(m0 + (lane >> 4) * 4 + r) * 640 + n0 + ni * 16 + (lane & 15)] = acc[ni][r];
}

// ---------------- Kernel S: batched linear Sinkhorn (4 lanes/token) + compose ----------------
__global__ __launch_bounds__(256) void k_sink(const float* __restrict__ logits,
                                              const float* __restrict__ a_pre_p, const float* __restrict__ H_pre,
                                              const float* __restrict__ a_al_p,  const float* __restrict__ H_al,
                                              const float* __restrict__ a_nx_p,  const float* __restrict__ H_nx,
                                              const float* __restrict__ a_po_p,  const float* __restrict__ H_po,
                                              float* __restrict__ Ppre,
                                              float* __restrict__ Pna, float* __restrict__ Pnp)
{
    __shared__ float Pal_sh[16 * 260];
    __shared__ float Pnx_sh[16 * 260];
    __shared__ float Ppo_sh[16 * 68];
    const int tid  = threadIdx.x;
    const int lane = tid & 63;
    const int wid  = tid >> 6;
    const int tok0 = blockIdx.x * 16;
    const int t_in = lane >> 2;
    const int sub  = lane & 3;
    const int tok  = tok0 + t_in;

    if (wid < 2) {
        const float alpha = (wid == 0) ? (*a_al_p) : (*a_nx_p);
        const float* Hp   = ((wid == 0) ? H_al : H_nx) + sub * 64;
        const float* lgp  = logits + (size_t)tok * 640 + (wid == 0 ? 64 : 320) + sub * 64;
        float Km[4][16];
        #pragma unroll
        for (int rr = 0; rr < 4; ++rr)
            #pragma unroll
            for (int c4 = 0; c4 < 4; ++c4) {
                float4 rv = *(const float4*)(lgp + rr * 16 + c4 * 4);
                float4 hv = *(const float4*)(Hp  + rr * 16 + c4 * 4);
                Km[rr][c4*4+0] = expf(alpha * rv.x + hv.x);
                Km[rr][c4*4+1] = expf(alpha * rv.y + hv.y);
                Km[rr][c4*4+2] = expf(alpha * rv.z + hv.z);
                Km[rr][c4*4+3] = expf(alpha * rv.w + hv.w);
            }
        float v[16], u[4];
        #pragma unroll
        for (int c = 0; c < 16; ++c) v[c] = 1.0f;
        for (int it = 0; it < ITERS; ++it) {
            #pragma unroll
            for (int rr = 0; rr < 4; ++rr) {
                float su = 0.f;
                #pragma unroll
                for (int c = 0; c < 16; ++c) su += Km[rr][c] * v[c];
                u[rr] = 0.0625f * __builtin_amdgcn_rcpf(su);
            }
            float pv[16];
            #pragma unroll
            for (int c = 0; c < 16; ++c)
                pv[c] = Km[0][c]*u[0] + Km[1][c]*u[1] + Km[2][c]*u[2] + Km[3][c]*u[3];
            #pragma unroll
            for (int c = 0; c < 16; ++c) pv[c] += __shfl_xor(pv[c], 1);
            #pragma unroll
            for (int c = 0; c < 16; ++c) pv[c] += __shfl_xor(pv[c], 2);
            #pragma unroll
            for (int c = 0; c < 16; ++c) v[c] = 0.0625f * __builtin_amdgcn_rcpf(pv[c]);
        }
        float* dst = ((wid == 0) ? Pal_sh : Pnx_sh) + t_in * 260;
        #pragma unroll
        for (int rr = 0; rr < 4; ++rr) {
            const float su16 = 16.0f * u[rr];
            #pragma unroll
            for (int c = 0; c < 16; ++c)
                dst[(sub * 4 + rr) * 16 + c] = Km[rr][c] * su16 * v[c];
        }
    } else if (wid == 2) {
        const float alpha = *a_pre_p;
        const float* lgp = logits + (size_t)tok * 640 + sub * 16;
        const float* Hp  = H_pre + sub * 16;
        float Km[16];
        #pragma unroll
        for (int c4 = 0; c4 < 4; ++c4) {
            float4 rv = *(const float4*)(lgp + c4 * 4);
            float4 hv = *(const float4*)(Hp  + c4 * 4);
            Km[c4*4+0] = expf(alpha * rv.x + hv.x);
            Km[c4*4+1] = expf(alpha * rv.y + hv.y);
            Km[c4*4+2] = expf(alpha * rv.z + hv.z);
            Km[c4*4+3] = expf(alpha * rv.w + hv.w);
        }
        float v[16], u;
        #pragma unroll
        for (int c = 0; c < 16; ++c) v[c] = 1.0f;
        for (int it = 0; it < ITERS; ++it) {
            float su = 0.f;
            #pragma unroll
            for (int c = 0; c < 16; ++c) su += Km[c] * v[c];
            u = 0.25f * __builtin_amdgcn_rcpf(su);
            float pv[16];
            #pragma unroll
            for (int c = 0; c < 16; ++c) pv[c] = Km[c] * u;
            #pragma unroll
            for (int c = 0; c < 16; ++c) pv[c] += __shfl_xor(pv[c], 1);
            #pragma unroll
            for (int c = 0; c < 16; ++c) pv[c] += __shfl_xor(pv[c], 2);
            #pragma unroll
            for (int c = 0; c < 16; ++c) v[c] = 0.0625f * __builtin_amdgcn_rcpf(pv[c]);
        }
        const float su4 = 4.0f * u;
        #pragma unroll
        for (int c = 0; c < 16; ++c)
            Ppre[(size_t)tok * 64 + sub * 16 + c] = Km[c] * su4 * v[c];
    } else {
        const float alpha = *a_po_p;
        const float* lgp = logits + (size_t)tok * 640 + 576 + sub * 16;
        const float* Hp  = H_po + sub * 16;
        float Km[4][4];
        #pragma unroll
        for (int rr = 0; rr < 4; ++rr) {
            float4 rv = *(const float4*)(lgp + rr * 4);
            float4 hv = *(const float4*)(Hp  + rr * 4);
            Km[rr][0] = expf(alpha * rv.x + hv.x);
            Km[rr][1] = expf(alpha * rv.y + hv.y);
            Km[rr][2] = expf(alpha * rv.z + hv.z);
            Km[rr][3] = expf(alpha * rv.w + hv.w);
        }
        float v[4], u[4];
        #pragma unroll
        for (int c = 0; c < 4; ++c) v[c] = 1.0f;
        for (int it = 0; it < ITERS; ++it) {
            #pragma unroll
            for (int rr = 0; rr < 4; ++rr) {
                float su = 0.f;
                #pragma unroll
                for (int c = 0; c < 4; ++c) su += Km[rr][c] * v[c];
                u[rr] = 0.0625f * __builtin_amdgcn_rcpf(su);
            }
            float pv[4];
            #pragma unroll
            for (int c = 0; c < 4; ++c)
                pv[c] = Km[0][c]*u[0] + Km[1][c]*u[1] + Km[2][c]*u[2] + Km[3][c]*u[3];
            #pragma unroll
            for (int c = 0; c < 4; ++c) pv[c] += __shfl_xor(pv[c], 1);
            #pragma unroll
            for (int c = 0; c < 4; ++c) pv[c] += __shfl_xor(pv[c], 2);
            #pragma unroll
            for (int c = 0; c < 4; ++c) v[c] = 0.25f * __builtin_amdgcn_rcpf(pv[c]);
        }
        #pragma unroll
        for (int rr = 0; rr < 4; ++rr) {
            const float su16 = 16.0f * u[rr];
            #pragma unroll
            for (int c = 0; c < 4; ++c)
                Ppo_sh[t_in * 68 + (sub * 4 + rr) * 4 + c] = Km[rr][c] * su16 * v[c];
        }
    }
    __syncthreads();

    const int ct = tid >> 4;
    const int cj = tid & 15;
    const float* pnx = Pnx_sh + ct * 260;
    const float* pal = Pal_sh + ct * 260;
    const float* ppo = Ppo_sh + ct * 68;
    #pragma unroll
    for (int m = 0; m < 16; ++m) {
        float acc = 0.f;
        #pragma unroll
        for (int t2 = 0; t2 < 16; ++t2) acc += pnx[m * 16 + t2] * pal[t2 * 16 + cj];
        Pna[(size_t)(tok0 + ct) * 256 + m * 16 + cj] = acc;
    }
    #pragma unroll
    for (int e = 0; e < 4; ++e) {
        const int idx = cj * 4 + e;
        const int m = idx >> 2, q = idx & 3;
        float acc = 0.f;
        #pragma unroll
        for (int t2 = 0; t2 < 16; ++t2) acc += pnx[m * 16 + t2] * ppo[t2 * 4 + q];
        Pnp[(size_t)(tok0 + ct) * 64 + idx] = acc;
    }
}

// ---------------- Kernel AP: layer_in = Ppre @ s ----------------
template<bool SBF>
__global__ __launch_bounds__(256) void k_apply2(const float* __restrict__ s,
                                                const unsigned short* __restrict__ s_bf,
                                                const float* __restrict__ Ppre,
                                                unsigned short* __restrict__ layer_in)
{
    __shared__ float s_sh[SD];
    __shared__ float P_sh[64];
    const int tid = threadIdx.x;
    const int tok = blockIdx.x;

    if (SBF) {
        #pragma unroll
        for (int c2 = 0; c2 < 2; ++c2) {
            ushort8 v = *(const ushort8*)(s_bf + (size_t)tok * SD + c2 * 2048 + tid * 8);
            float4 f0, f1;
            f0.x = bf2f(v[0]); f0.y = bf2f(v[1]); f0.z = bf2f(v[2]); f0.w = bf2f(v[3]);
            f1.x = bf2f(v[4]); f1.y = bf2f(v[5]); f1.z = bf2f(v[6]); f1.w = bf2f(v[7]);
            *(float4*)(s_sh + c2 * 2048 + tid * 8)     = f0;
            *(float4*)(s_sh + c2 * 2048 + tid * 8 + 4) = f1;
        }
    } else {
        const float4* sp4 = (const float4*)(s + (size_t)tok * SD);
        #pragma unroll
        for (int j = 0; j < 4; ++j)
            *(float4*)(s_sh + j * 1024 + tid * 4) = sp4[j * 256 + tid];
    }
    if (tid < 64) P_sh[tid] = Ppre[(size_t)tok * 64 + tid];
    __syncthreads();

    #pragma unroll
    for (int i = 0; i < 4; ++i) {
        float acc = 0.f;
        #pragma unroll
        for (int j = 0; j < 16; ++j) acc += P_sh[i * 16 + j] * s_sh[j * 256 + tid];
        layer_in[(size_t)tok * 1024 + i * 256 + tid] = f2bf(acc);
    }
}

// ---------------- Kernel C: layer_out(bf16) = layer_in @ WT^T via MFMA ----------------
__global__ __launch_bounds__(256) void k_gemm_bf16(const unsigned short* __restrict__ A,
                                                   const unsigned short* __restrict__ BT,
                                                   unsigned short* __restrict__ Cb)
{
    __shared__ unsigned short Abuf[128 * 48];
    __shared__ unsigned short Bbuf[128 * 48];
    const int tid  = threadIdx.x;
    const int lane = tid & 63;
    const int wid  = tid >> 6;
    const int wr   = wid >> 1, wc = wid & 1;
    const int m0 = blockIdx.y * 128, n0 = blockIdx.x * 128;

    f32x4 acc[4][4];
    #pragma unroll
    for (int mi = 0; mi < 4; ++mi)
        #pragma unroll
        for (int ni = 0; ni < 4; ++ni) acc[mi][ni] = (f32x4){0.f, 0.f, 0.f, 0.f};

    for (int k0 = 0; k0 < 1024; k0 += 32) {
        __syncthreads();
        #pragma unroll
        for (int h = 0; h < 2; ++h) {
            const int idx = h * 256 + tid;
            const int row = idx >> 2, kq = idx & 3;
            float4 av = *(const float4*)(A + (size_t)(m0 + row) * 1024 + k0 + kq * 8);
            *(float4*)(Abuf + row * 48 + kq * 8) = av;
            float4 bv = *(const float4*)(BT + (size_t)(n0 + row) * 1024 + k0 + kq * 8);
            *(float4*)(Bbuf + row * 48 + kq * 8) = bv;
        }
        __syncthreads();

        short8 a[4], b[4];
        #pragma unroll
        for (int mi = 0; mi < 4; ++mi)
            a[mi] = *(const short8*)(Abuf + (wr * 64 + mi * 16 + (lane & 15)) * 48 + (lane >> 4) * 8);
        #pragma unroll
        for (int ni = 0; ni < 4; ++ni)
            b[ni] = *(const short8*)(Bbuf + (wc * 64 + ni * 16 + (lane & 15)) * 48 + (lane >> 4) * 8);
        #pragma unroll
        for (int mi = 0; mi < 4; ++mi)
            #pragma unroll
            for (int ni = 0; ni < 4; ++ni)
                acc[mi][ni] = __builtin_amdgcn_mfma_f32_16x16x32_bf16(a[mi], b[ni], acc[mi][ni], 0, 0, 0);
    }

    #pragma unroll
    for (int mi = 0; mi < 4; ++mi)
        #pragma unroll
        for (int ni = 0; ni < 4; ++ni)
            #pragma unroll
            for (int r = 0; r < 4; ++r)
                Cb[(size_t)(m0 + wr * 64 + mi * 16 + (lane >> 4) * 4 + r) * 1024 +
                   n0 + wc * 64 + ni * 16 + (lane & 15)] = f2bf(acc[mi][ni][r]);
}

// ---------------- Kernel D: s_next = P_na @ s + P_np @ layer_out ----------------
template<bool SBF>
__global__ __launch_bounds__(256) void k_final2(const float* __restrict__ s,
                                                const unsigned short* __restrict__ s_bf,
                                                const unsigned short* __restrict__ lo_bf,
                                                const float* __restrict__ Pna,
                                                const float* __restrict__ Pnp,
                                                float* __restrict__ out)
{
    __shared__ float s_sh[SD];
    __shared__ float lo_sh[1024];
    __shared__ float Pna_sh[256];
    __shared__ float Pnp_sh[64];
    const int tid = threadIdx.x;
    const int tok = blockIdx.x;

    if (SBF) {
        #pragma unroll
        for (int c2 = 0; c2 < 2; ++c2) {
            ushort8 v = *(const ushort8*)(s_bf + (size_t)tok * SD + c2 * 2048 + tid * 8);
            float4 f0, f1;
            f0.x = bf2f(v[0]); f0.y = bf2f(v[1]); f0.z = bf2f(v[2]); f0.w = bf2f(v[3]);
            f1.x = bf2f(v[4]); f1.y = bf2f(v[5]); f1.z = bf2f(v[6]); f1.w = bf2f(v[7]);
            *(float4*)(s_sh + c2 * 2048 + tid * 8)     = f0;
            *(float4*)(s_sh + c2 * 2048 + tid * 8 + 4) = f1;
        }
    } else {
        const float4* sp4 = (const float4*)(s + (size_t)tok * SD);
        #pragma unroll
        for (int j = 0; j < 4; ++j)
            *(float4*)(s_sh + j * 1024 + tid * 4) = sp4[j * 256 + tid];
    }
    {
        us4 lv = *(const us4*)(lo_bf + (size_t)tok * 1024 + tid * 4);
        float4 f;
        f.x = bf2f(lv[0]); f.y = bf2f(lv[1]); f.z = bf2f(lv[2]); f.w = bf2f(lv[3]);
        *(float4*)(lo_sh + tid * 4) = f;
    }
    Pna_sh[tid] = Pna[(size_t)tok * 256 + tid];
    if (tid < 64) Pnp_sh[tid] = Pnp[(size_t)tok * 64 + tid];
    __syncthreads();

    const int c = tid;
    #pragma unroll
    for (int m = 0; m < 16; ++m) {
        float acc = 0.f;
        #pragma unroll
        for (int j = 0; j < 16; ++j) acc += Pna_sh[m * 16 + j] * s_sh[j * 256 + c];
        #pragma unroll
        for (int q = 0; q < 4; ++q) acc += Pnp_sh[m * 4 + q] * lo_sh[q * 256 + c];
        out[(size_t)tok * SD + m * 256 + c] = acc;
    }
}

extern "C" void kernel_launch(void* const* d_in, const int* in_sizes, int n_in,
                              void* d_out, int out_size, void* d_ws, size_t ws_size,
                              hipStream_t stream)
{
    const float* s        = (const float*)d_in[0];
    const float* gamma    = (const float*)d_in[1];
    const float* compress = (const float*)d_in[2];
    const float* a_pre    = (const float*)d_in[3];
    const float* tl_pre   = (const float*)d_in[4];
    const float* H_pre    = (const float*)d_in[5];
    const float* a_al     = (const float*)d_in[6];
    const float* tl_al    = (const float*)d_in[7];
    const float* H_al     = (const float*)d_in[8];
    const float* a_nx     = (const float*)d_in[9];
    const float* tl_nx    = (const float*)d_in[10];
    const float* H_nx     = (const float*)d_in[11];
    const float* a_po     = (const float*)d_in[12];
    const float* tl_po    = (const float*)d_in[13];
    const float* H_po     = (const float*)d_in[14];
    const float* W        = (const float*)d_in[15];
    float* out = (float*)d_out;

    char* p = (char*)d_ws;
    float* layer_out         = (float*)p;          p += (size_t)8192 * 1024 * 4;  // logits alias + lo_bf alias
    float* logits            = layer_out;
    unsigned short* lo_bf    = (unsigned short*)layer_out;
    float* Pna               = (float*)p;          p += (size_t)8192 * 256 * 4;
    float* Pnp               = (float*)p;          p += (size_t)8192 * 64 * 4;
    unsigned short* layer_in = (unsigned short*)p; p += (size_t)8192 * 1024 * 2;
    unsigned short* WT       = (unsigned short*)p; p += (size_t)1024 * 1024 * 2;
    unsigned short* cgT      = (unsigned short*)p; p += (size_t)64 * SD * 2;
    unsigned short* codeBF   = (unsigned short*)p; p += (size_t)8192 * 64 * 2;
    unsigned short* tlT      = (unsigned short*)p; p += (size_t)640 * 64 * 2 + 128;
    float* Ppre              = (float*)p;          p += (size_t)8192 * 64 * 4;
    unsigned short* s_bf     = (unsigned short*)p; p += (size_t)NTOK * SD * 2;
    const bool use_sbf = ((size_t)(p - (char*)d_ws) <= ws_size);

    k_wt<<<dim3(16, 16), 256, 0, stream>>>(W, WT);
    k_prep<<<64, 256, 0, stream>>>(compress, gamma, cgT);
    k_prept<<<160, 256, 0, stream>>>(tl_pre, tl_al, tl_nx, tl_po, tlT);
    k_code4<<<512, 256, 0, stream>>>(s, cgT, codeBF, use_sbf ? s_bf : (unsigned short*)nullptr);
    k_logits<<<dim3(5, 128), 256, 0, stream>>>(codeBF, tlT, logits);
    k_sink<<<512, 256, 0, stream>>>(logits,
                                    a_pre, H_pre, a_al, H_al,
                                    a_nx, H_nx, a_po, H_po,
                                    Ppre, Pna, Pnp);
    if (use_sbf) {
        k_apply2<true><<<NTOK, 256, 0, stream>>>(s, s_bf, Ppre, layer_in);
    } else {
        k_apply2<false><<<NTOK, 256, 0, stream>>>(s, s_bf, Ppre, layer_in);
    }
    k_gemm_bf16<<<dim3(8, 64), 256, 0, stream>>>(layer_in, WT, lo_bf);
    if (use_sbf) {
        k_final2<true><<<NTOK, 256, 0, stream>>>(s, s_bf, lo_bf, Pna, Pnp, out);
    } else {
        k_final2<false><<<NTOK, 256, 0, stream>>>(s, s_bf, lo_bf, Pna, Pnp, out);
    }
}

// Round 7
// 195.896 us; speedup vs baseline: 1.0949x; 1.0949x over previous
//
#include <hip/hip_runtime.h>
#include <math.h>

#define NTOK 8192
#define SD   4096
#define ITERS 20

typedef __attribute__((ext_vector_type(8))) short short8;
typedef __attribute__((ext_vector_type(8))) unsigned short ushort8;
typedef __attribute__((ext_vector_type(4))) unsigned short us4;
typedef __attribute__((ext_vector_type(4))) float f32x4;

__device__ inline unsigned short f2bf(float x) {
    unsigned int u = __float_as_uint(x);
    unsigned int r = (u + 0x7FFFu + ((u >> 16) & 1u)) >> 16;
    return (unsigned short)r;
}
__device__ inline float bf2f(unsigned short u) {
    return __uint_as_float((unsigned int)u << 16);
}

// ---------------- Kernel PREALL: fused k_wt (blocks 0-255) + k_prep (256-319) + k_prept (320-479) ----------------
__global__ __launch_bounds__(256) void k_preall(const float* __restrict__ W, unsigned short* __restrict__ WT,
                                                const float* __restrict__ compress, const float* __restrict__ gamma,
                                                unsigned short* __restrict__ cgT,
                                                const float* __restrict__ tl_pre, const float* __restrict__ tl_al,
                                                const float* __restrict__ tl_nx,  const float* __restrict__ tl_po,
                                                unsigned short* __restrict__ tlT)
{
    const int b = blockIdx.x;
    const int tid = threadIdx.x;
    if (b < 256) {
        __shared__ float tb[64][65];
        const int k0 = (b >> 4) * 64, n0 = (b & 15) * 64;
        #pragma unroll 4
        for (int q = 0; q < 16; ++q) {
            const int idx = q * 256 + tid;
            const int r = idx >> 6, c = idx & 63;
            tb[r][c] = W[(size_t)(k0 + r) * 1024 + n0 + c];
        }
        __syncthreads();
        #pragma unroll 4
        for (int q = 0; q < 16; ++q) {
            const int idx = q * 256 + tid;
            const int n = idx >> 6, k = idx & 63;
            WT[(size_t)(n0 + n) * 1024 + k0 + k] = f2bf(tb[k][n]);
        }
    } else if (b < 320) {
        __shared__ float tb2[64][65];
        __shared__ float gsh[64];
        const int k0 = (b - 256) * 64;
        #pragma unroll 4
        for (int q = 0; q < 16; ++q) {
            const int idx = q * 256 + tid;
            const int r = idx >> 6, dd = idx & 63;
            tb2[r][dd] = compress[(size_t)(k0 + r) * 64 + dd];
        }
        if (tid < 64) gsh[tid] = gamma[k0 + tid] + 1.0f;
        __syncthreads();
        #pragma unroll 4
        for (int q = 0; q < 16; ++q) {
            const int idx = q * 256 + tid;
            const int d = idx >> 6, r = idx & 63;
            cgT[(size_t)d * SD + k0 + r] = f2bf(tb2[r][d] * gsh[r]);
        }
    } else {
        const int idx = (b - 320) * 256 + tid;
        const int k = idx / 640, n = idx - k * 640;
        float v;
        if (n < 64)       v = tl_pre[k * 64 + n];
        else if (n < 320) v = tl_al[k * 256 + (n - 64)];
        else if (n < 576) v = tl_nx[k * 256 + (n - 320)];
        else              v = tl_po[k * 64 + (n - 576)];
        tlT[(size_t)n * 64 + k] = f2bf(v);
    }
}

// ---------------- Kernel FRONT: code(MFMA) -> logits(MFMA,LDS) -> 4 linear Sinkhorns -> compose ----------------
// 512 blocks x 16 tokens, 256 threads. Also emits s_bf (bf16 copy of s) if non-null.
__global__ __launch_bounds__(256) void k_front(const float* __restrict__ s,
                                               const unsigned short* __restrict__ cgT,
                                               const unsigned short* __restrict__ tlT,
                                               const float* __restrict__ a_pre_p, const float* __restrict__ H_pre,
                                               const float* __restrict__ a_al_p,  const float* __restrict__ H_al,
                                               const float* __restrict__ a_nx_p,  const float* __restrict__ H_nx,
                                               const float* __restrict__ a_po_p,  const float* __restrict__ H_po,
                                               float* __restrict__ Ppre,
                                               float* __restrict__ Pna, float* __restrict__ Pnp,
                                               unsigned short* __restrict__ s_bf)
{
    // LDS layout (phased aliasing):
    //  [0,2304)       code_sh  ushort[16*72]              (lives: phaseB -> phaseC)
    //  [2304,26624)   regionA: s_sh[16*152]us + cg_sh[64*152]us  |  red f32[4*16*68]  |  lg_sh us[16*656]
    //  [26624,64256)  Pal f32[16*260] @26624, Pnx @43264, Ppo f32[16*68] @59904   (phaseD -> phaseE)
    //  [64256,64320)  ssq_sh f32[16]
    __shared__ __align__(16) char smem[64320];
    unsigned short* code_sh = (unsigned short*)(smem);
    unsigned short* s_sh    = (unsigned short*)(smem + 2304);
    unsigned short* cg_sh   = (unsigned short*)(smem + 2304 + 4864);
    float*          red     = (float*)(smem + 2304);
    unsigned short* lg_sh   = (unsigned short*)(smem + 2304);
    float*          Pal_sh  = (float*)(smem + 26624);
    float*          Pnx_sh  = (float*)(smem + 43264);
    float*          Ppo_sh  = (float*)(smem + 59904);
    float*          ssq_sh  = (float*)(smem + 64256);

    const int tid  = threadIdx.x;
    const int lane = tid & 63;
    const int wid  = tid >> 6;
    const int tok0 = blockIdx.x * 16;
    const int st_tok = tid >> 4;        // 16 threads per token
    const int st_k   = (tid & 15) * 8;  // 8 f32 each
    const int sg_d   = tid >> 2;
    const int sg_k   = (tid & 3) * 32;
    const int wk = wid * 32;

    // ---- phase A: K-loop, code partials ----
    float ssq = 0.f;
    f32x4 acc[4];
    #pragma unroll
    for (int ni = 0; ni < 4; ++ni) acc[ni] = (f32x4){0.f, 0.f, 0.f, 0.f};

    for (int ks = 0; ks < 32; ++ks) {
        const int kg = ks * 128;
        __syncthreads();  // WAR guard
        {
            const float4* sp = (const float4*)(s + (size_t)(tok0 + st_tok) * SD + kg + st_k);
            float4 v0 = sp[0], v1 = sp[1];
            ssq += v0.x*v0.x + v0.y*v0.y + v0.z*v0.z + v0.w*v0.w
                 + v1.x*v1.x + v1.y*v1.y + v1.z*v1.z + v1.w*v1.w;
            ushort8 pk;
            pk[0]=f2bf(v0.x); pk[1]=f2bf(v0.y); pk[2]=f2bf(v0.z); pk[3]=f2bf(v0.w);
            pk[4]=f2bf(v1.x); pk[5]=f2bf(v1.y); pk[6]=f2bf(v1.z); pk[7]=f2bf(v1.w);
            *(ushort8*)(s_sh + st_tok * 152 + st_k) = pk;
            if (s_bf)
                *(ushort8*)(s_bf + (size_t)(tok0 + st_tok) * SD + kg + st_k) = pk;
        }
        {
            const ushort8* gp = (const ushort8*)(cgT + (size_t)sg_d * SD + kg + sg_k);
            ushort8 c0 = gp[0], c1 = gp[1], c2 = gp[2], c3 = gp[3];
            ushort8* cw = (ushort8*)(cg_sh + sg_d * 152 + sg_k);
            cw[0] = c0; cw[1] = c1; cw[2] = c2; cw[3] = c3;
        }
        __syncthreads();

        short8 a = *(const short8*)(s_sh + (lane & 15) * 152 + wk + (lane >> 4) * 8);
        short8 b[4];
        #pragma unroll
        for (int ni = 0; ni < 4; ++ni)
            b[ni] = *(const short8*)(cg_sh + (ni * 16 + (lane & 15)) * 152 + wk + (lane >> 4) * 8);
        #pragma unroll
        for (int ni = 0; ni < 4; ++ni)
            acc[ni] = __builtin_amdgcn_mfma_f32_16x16x32_bf16(a, b[ni], acc[ni], 0, 0, 0);
    }

    ssq += __shfl_xor(ssq, 1);
    ssq += __shfl_xor(ssq, 2);
    ssq += __shfl_xor(ssq, 4);
    ssq += __shfl_xor(ssq, 8);
    __syncthreads();  // all waves done reading s_sh/cg_sh before red (alias) is written
    if ((tid & 15) == 0) ssq_sh[st_tok] = ssq;

    // ---- phase B: per-wave partials -> reduce -> code_sh (bf16) ----
    #pragma unroll
    for (int ni = 0; ni < 4; ++ni)
        #pragma unroll
        for (int r = 0; r < 4; ++r)
            red[wid * 1088 + ((lane >> 4) * 4 + r) * 68 + ni * 16 + (lane & 15)] = acc[ni][r];
    __syncthreads();
    if (tid < 16) ssq_sh[tid] = 64.0f / fmaxf(sqrtf(ssq_sh[tid]), 1e-12f);
    __syncthreads();
    #pragma unroll
    for (int q = 0; q < 4; ++q) {
        const int idx = q * 256 + tid;
        const int tok = idx >> 6, d = idx & 63;
        float v = red[0 * 1088 + tok * 68 + d] + red[1 * 1088 + tok * 68 + d]
                + red[2 * 1088 + tok * 68 + d] + red[3 * 1088 + tok * 68 + d];
        code_sh[tok * 72 + d] = f2bf(v * ssq_sh[tok]);
    }
    __syncthreads();  // code_sh ready; red dead -> lg_sh may be written

    // ---- phase C: logits[16][640] = code @ tlcat^T (MFMA), bf16 into lg_sh ----
    {
        f32x4 acc2[10];
        #pragma unroll
        for (int ni = 0; ni < 10; ++ni) acc2[ni] = (f32x4){0.f, 0.f, 0.f, 0.f};
        const int nbase = wid * 160;
        #pragma unroll
        for (int ks = 0; ks < 2; ++ks) {
            const int ko = ks * 32 + (lane >> 4) * 8;
            short8 a = *(const short8*)(code_sh + (lane & 15) * 72 + ko);
            #pragma unroll
            for (int ni = 0; ni < 10; ++ni) {
                short8 b = *(const short8*)(tlT + (size_t)(nbase + ni * 16 + (lane & 15)) * 64 + ko);
                acc2[ni] = __builtin_amdgcn_mfma_f32_16x16x32_bf16(a, b, acc2[ni], 0, 0, 0);
            }
        }
        #pragma unroll
        for (int ni = 0; ni < 10; ++ni)
            #pragma unroll
            for (int r = 0; r < 4; ++r)
                lg_sh[((lane >> 4) * 4 + r) * 656 + nbase + ni * 16 + (lane & 15)] = f2bf(acc2[ni][r]);
    }
    __syncthreads();

    // ---- phase D: linear Sinkhorns (4 lanes per token) ----
    const int t_in = lane >> 2;
    const int sub  = lane & 3;
    const int tok  = tok0 + t_in;

    if (wid < 2) {
        const float alpha = (wid == 0) ? (*a_al_p) : (*a_nx_p);
        const float* Hp   = ((wid == 0) ? H_al : H_nx) + sub * 64;
        const unsigned short* lgp = lg_sh + t_in * 656 + (wid == 0 ? 64 : 320) + sub * 64;
        float Km[4][16];
        #pragma unroll
        for (int rr = 0; rr < 4; ++rr)
            #pragma unroll
            for (int h = 0; h < 2; ++h) {
                ushort8 rv = *(const ushort8*)(lgp + rr * 16 + h * 8);
                float4 h0 = *(const float4*)(Hp + rr * 16 + h * 8);
                float4 h1 = *(const float4*)(Hp + rr * 16 + h * 8 + 4);
                Km[rr][h*8+0] = expf(alpha * bf2f(rv[0]) + h0.x);
                Km[rr][h*8+1] = expf(alpha * bf2f(rv[1]) + h0.y);
                Km[rr][h*8+2] = expf(alpha * bf2f(rv[2]) + h0.z);
                Km[rr][h*8+3] = expf(alpha * bf2f(rv[3]) + h0.w);
                Km[rr][h*8+4] = expf(alpha * bf2f(rv[4]) + h1.x);
                Km[rr][h*8+5] = expf(alpha * bf2f(rv[5]) + h1.y);
                Km[rr][h*8+6] = expf(alpha * bf2f(rv[6]) + h1.z);
                Km[rr][h*8+7] = expf(alpha * bf2f(rv[7]) + h1.w);
            }
        float v[16], u[4];
        #pragma unroll
        for (int c = 0; c < 16; ++c) v[c] = 1.0f;
        for (int it = 0; it < ITERS; ++it) {
            #pragma unroll
            for (int rr = 0; rr < 4; ++rr) {
                float su = 0.f;
                #pragma unroll
                for (int c = 0; c < 16; ++c) su += Km[rr][c] * v[c];
                u[rr] = 0.0625f * __builtin_amdgcn_rcpf(su);
            }
            float pv[16];
            #pragma unroll
            for (int c = 0; c < 16; ++c)
                pv[c] = Km[0][c]*u[0] + Km[1][c]*u[1] + Km[2][c]*u[2] + Km[3][c]*u[3];
            #pragma unroll
            for (int c = 0; c < 16; ++c) pv[c] += __shfl_xor(pv[c], 1);
            #pragma unroll
            for (int c = 0; c < 16; ++c) pv[c] += __shfl_xor(pv[c], 2);
            #pragma unroll
            for (int c = 0; c < 16; ++c) v[c] = 0.0625f * __builtin_amdgcn_rcpf(pv[c]);
        }
        float* dst = ((wid == 0) ? Pal_sh : Pnx_sh) + t_in * 260;
        #pragma unroll
        for (int rr = 0; rr < 4; ++rr) {
            const float su16 = 16.0f * u[rr];
            #pragma unroll
            for (int c = 0; c < 16; ++c)
                dst[(sub * 4 + rr) * 16 + c] = Km[rr][c] * su16 * v[c];
        }
    } else if (wid == 2) {
        const float alpha = *a_pre_p;
        const unsigned short* lgp = lg_sh + t_in * 656 + sub * 16;
        const float* Hp  = H_pre + sub * 16;
        float Km[16];
        #pragma unroll
        for (int h = 0; h < 2; ++h) {
            ushort8 rv = *(const ushort8*)(lgp + h * 8);
            float4 h0 = *(const float4*)(Hp + h * 8);
            float4 h1 = *(const float4*)(Hp + h * 8 + 4);
            Km[h*8+0] = expf(alpha * bf2f(rv[0]) + h0.x);
            Km[h*8+1] = expf(alpha * bf2f(rv[1]) + h0.y);
            Km[h*8+2] = expf(alpha * bf2f(rv[2]) + h0.z);
            Km[h*8+3] = expf(alpha * bf2f(rv[3]) + h0.w);
            Km[h*8+4] = expf(alpha * bf2f(rv[4]) + h1.x);
            Km[h*8+5] = expf(alpha * bf2f(rv[5]) + h1.y);
            Km[h*8+6] = expf(alpha * bf2f(rv[6]) + h1.z);
            Km[h*8+7] = expf(alpha * bf2f(rv[7]) + h1.w);
        }
        float v[16], u;
        #pragma unroll
        for (int c = 0; c < 16; ++c) v[c] = 1.0f;
        for (int it = 0; it < ITERS; ++it) {
            float su = 0.f;
            #pragma unroll
            for (int c = 0; c < 16; ++c) su += Km[c] * v[c];
            u = 0.25f * __builtin_amdgcn_rcpf(su);
            float pv[16];
            #pragma unroll
            for (int c = 0; c < 16; ++c) pv[c] = Km[c] * u;
            #pragma unroll
            for (int c = 0; c < 16; ++c) pv[c] += __shfl_xor(pv[c], 1);
            #pragma unroll
            for (int c = 0; c < 16; ++c) pv[c] += __shfl_xor(pv[c], 2);
            #pragma unroll
            for (int c = 0; c < 16; ++c) v[c] = 0.0625f * __builtin_amdgcn_rcpf(pv[c]);
        }
        const float su4 = 4.0f * u;
        #pragma unroll
        for (int c = 0; c < 16; ++c)
            Ppre[(size_t)tok * 64 + sub * 16 + c] = Km[c] * su4 * v[c];
    } else {
        const float alpha = *a_po_p;
        const unsigned short* lgp = lg_sh + t_in * 656 + 576 + sub * 16;
        const float* Hp  = H_po + sub * 16;
        float Km[4][4];
        #pragma unroll
        for (int rr = 0; rr < 4; ++rr) {
            us4 rv = *(const us4*)(lgp + rr * 4);
            float4 hv = *(const float4*)(Hp + rr * 4);
            Km[rr][0] = expf(alpha * bf2f(rv[0]) + hv.x);
            Km[rr][1] = expf(alpha * bf2f(rv[1]) + hv.y);
            Km[rr][2] = expf(alpha * bf2f(rv[2]) + hv.z);
            Km[rr][3] = expf(alpha * bf2f(rv[3]) + hv.w);
        }
        float v[4], u[4];
        #pragma unroll
        for (int c = 0; c < 4; ++c) v[c] = 1.0f;
        for (int it = 0; it < ITERS; ++it) {
            #pragma unroll
            for (int rr = 0; rr < 4; ++rr) {
                float su = 0.f;
                #pragma unroll
                for (int c = 0; c < 4; ++c) su += Km[rr][c] * v[c];
                u[rr] = 0.0625f * __builtin_amdgcn_rcpf(su);
            }
            float pv[4];
            #pragma unroll
            for (int c = 0; c < 4; ++c)
                pv[c] = Km[0][c]*u[0] + Km[1][c]*u[1] + Km[2][c]*u[2] + Km[3][c]*u[3];
            #pragma unroll
            for (int c = 0; c < 4; ++c) pv[c] += __shfl_xor(pv[c], 1);
            #pragma unroll
            for (int c = 0; c < 4; ++c) pv[c] += __shfl_xor(pv[c], 2);
            #pragma unroll
            for (int c = 0; c < 4; ++c) v[c] = 0.25f * __builtin_amdgcn_rcpf(pv[c]);
        }
        #pragma unroll
        for (int rr = 0; rr < 4; ++rr) {
            const float su16 = 16.0f * u[rr];
            #pragma unroll
            for (int c = 0; c < 4; ++c)
                Ppo_sh[t_in * 68 + (sub * 4 + rr) * 4 + c] = Km[rr][c] * su16 * v[c];
        }
    }
    __syncthreads();

    // ---- phase E: compose Pna = Pnx@Pal, Pnp = Pnx@Ppo ----
    const int ct = tid >> 4;
    const int cj = tid & 15;
    const float* pnx = Pnx_sh + ct * 260;
    const float* pal = Pal_sh + ct * 260;
    const float* ppo = Ppo_sh + ct * 68;
    #pragma unroll
    for (int m = 0; m < 16; ++m) {
        float a2 = 0.f;
        #pragma unroll
        for (int t2 = 0; t2 < 16; ++t2) a2 += pnx[m * 16 + t2] * pal[t2 * 16 + cj];
        Pna[(size_t)(tok0 + ct) * 256 + m * 16 + cj] = a2;
    }
    #pragma unroll
    for (int e = 0; e < 4; ++e) {
        const int idx = cj * 4 + e;
        const int m = idx >> 2, q = idx & 3;
        float a2 = 0.f;
        #pragma unroll
        for (int t2 = 0; t2 < 16; ++t2) a2 += pnx[m * 16 + t2] * ppo[t2 * 4 + q];
        Pnp[(size_t)(tok0 + ct) * 64 + idx] = a2;
    }
}

// ---------------- Kernel AP: layer_in = Ppre @ s ----------------
template<bool SBF>
__global__ __launch_bounds__(256) void k_apply2(const float* __restrict__ s,
                                                const unsigned short* __restrict__ s_bf,
                                                const float* __restrict__ Ppre,
                                                unsigned short* __restrict__ layer_in)
{
    __shared__ float s_sh[SD];
    __shared__ float P_sh[64];
    const int tid = threadIdx.x;
    const int tok = blockIdx.x;

    if (SBF) {
        #pragma unroll
        for (int c2 = 0; c2 < 2; ++c2) {
            ushort8 v = *(const ushort8*)(s_bf + (size_t)tok * SD + c2 * 2048 + tid * 8);
            float4 f0, f1;
            f0.x = bf2f(v[0]); f0.y = bf2f(v[1]); f0.z = bf2f(v[2]); f0.w = bf2f(v[3]);
            f1.x = bf2f(v[4]); f1.y = bf2f(v[5]); f1.z = bf2f(v[6]); f1.w = bf2f(v[7]);
            *(float4*)(s_sh + c2 * 2048 + tid * 8)     = f0;
            *(float4*)(s_sh + c2 * 2048 + tid * 8 + 4) = f1;
        }
    } else {
        const float4* sp4 = (const float4*)(s + (size_t)tok * SD);
        #pragma unroll
        for (int j = 0; j < 4; ++j)
            *(float4*)(s_sh + j * 1024 + tid * 4) = sp4[j * 256 + tid];
    }
    if (tid < 64) P_sh[tid] = Ppre[(size_t)tok * 64 + tid];
    __syncthreads();

    #pragma unroll
    for (int i = 0; i < 4; ++i) {
        float acc = 0.f;
        #pragma unroll
        for (int j = 0; j < 16; ++j) acc += P_sh[i * 16 + j] * s_sh[j * 256 + tid];
        layer_in[(size_t)tok * 1024 + i * 256 + tid] = f2bf(acc);
    }
}

// ---------------- Kernel C: layer_out(bf16) = layer_in @ WT^T via MFMA ----------------
__global__ __launch_bounds__(256) void k_gemm_bf16(const unsigned short* __restrict__ A,
                                                   const unsigned short* __restrict__ BT,
                                                   unsigned short* __restrict__ Cb)
{
    __shared__ unsigned short Abuf[128 * 48];
    __shared__ unsigned short Bbuf[128 * 48];
    const int tid  = threadIdx.x;
    const int lane = tid & 63;
    const int wid  = tid >> 6;
    const int wr   = wid >> 1, wc = wid & 1;
    const int m0 = blockIdx.y * 128, n0 = blockIdx.x * 128;

    f32x4 acc[4][4];
    #pragma unroll
    for (int mi = 0; mi < 4; ++mi)
        #pragma unroll
        for (int ni = 0; ni < 4; ++ni) acc[mi][ni] = (f32x4){0.f, 0.f, 0.f, 0.f};

    for (int k0 = 0; k0 < 1024; k0 += 32) {
        __syncthreads();
        #pragma unroll
        for (int h = 0; h < 2; ++h) {
            const int idx = h * 256 + tid;
            const int row = idx >> 2, kq = idx & 3;
            float4 av = *(const float4*)(A + (size_t)(m0 + row) * 1024 + k0 + kq * 8);
            *(float4*)(Abuf + row * 48 + kq * 8) = av;
            float4 bv = *(const float4*)(BT + (size_t)(n0 + row) * 1024 + k0 + kq * 8);
            *(float4*)(Bbuf + row * 48 + kq * 8) = bv;
        }
        __syncthreads();

        short8 a[4], b[4];
        #pragma unroll
        for (int mi = 0; mi < 4; ++mi)
            a[mi] = *(const short8*)(Abuf + (wr * 64 + mi * 16 + (lane & 15)) * 48 + (lane >> 4) * 8);
        #pragma unroll
        for (int ni = 0; ni < 4; ++ni)
            b[ni] = *(const short8*)(Bbuf + (wc * 64 + ni * 16 + (lane & 15)) * 48 + (lane >> 4) * 8);
        #pragma unroll
        for (int mi = 0; mi < 4; ++mi)
            #pragma unroll
            for (int ni = 0; ni < 4; ++ni)
                acc[mi][ni] = __builtin_amdgcn_mfma_f32_16x16x32_bf16(a[mi], b[ni], acc[mi][ni], 0, 0, 0);
    }

    #pragma unroll
    for (int mi = 0; mi < 4; ++mi)
        #pragma unroll
        for (int ni = 0; ni < 4; ++ni)
            #pragma unroll
            for (int r = 0; r < 4; ++r)
                Cb[(size_t)(m0 + wr * 64 + mi * 16 + (lane >> 4) * 4 + r) * 1024 +
                   n0 + wc * 64 + ni * 16 + (lane & 15)] = f2bf(acc[mi][ni][r]);
}

// ---------------- Kernel D: s_next = P_na @ s + P_np @ layer_out ----------------
template<bool SBF>
__global__ __launch_bounds__(256) void k_final2(const float* __restrict__ s,
                                                const unsigned short* __restrict__ s_bf,
                                                const unsigned short* __restrict__ lo_bf,
                                                const float* __restrict__ Pna,
                                                const float* __restrict__ Pnp,
                                                float* __restrict__ out)
{
    __shared__ float s_sh[SD];
    __shared__ float lo_sh[1024];
    __shared__ float Pna_sh[256];
    __shared__ float Pnp_sh[64];
    const int tid = threadIdx.x;
    const int tok = blockIdx.x;

    if (SBF) {
        #pragma unroll
        for (int c2 = 0; c2 < 2; ++c2) {
            ushort8 v = *(const ushort8*)(s_bf + (size_t)tok * SD + c2 * 2048 + tid * 8);
            float4 f0, f1;
            f0.x = bf2f(v[0]); f0.y = bf2f(v[1]); f0.z = bf2f(v[2]); f0.w = bf2f(v[3]);
            f1.x = bf2f(v[4]); f1.y = bf2f(v[5]); f1.z = bf2f(v[6]); f1.w = bf2f(v[7]);
            *(float4*)(s_sh + c2 * 2048 + tid * 8)     = f0;
            *(float4*)(s_sh + c2 * 2048 + tid * 8 + 4) = f1;
        }
    } else {
        const float4* sp4 = (const float4*)(s + (size_t)tok * SD);
        #pragma unroll
        for (int j = 0; j < 4; ++j)
            *(float4*)(s_sh + j * 1024 + tid * 4) = sp4[j * 256 + tid];
    }
    {
        us4 lv = *(const us4*)(lo_bf + (size_t)tok * 1024 + tid * 4);
        float4 f;
        f.x = bf2f(lv[0]); f.y = bf2f(lv[1]); f.z = bf2f(lv[2]); f.w = bf2f(lv[3]);
        *(float4*)(lo_sh + tid * 4) = f;
    }
    Pna_sh[tid] = Pna[(size_t)tok * 256 + tid];
    if (tid < 64) Pnp_sh[tid] = Pnp[(size_t)tok * 64 + tid];
    __syncthreads();

    const int c = tid;
    #pragma unroll
    for (int m = 0; m < 16; ++m) {
        float acc = 0.f;
        #pragma unroll
        for (int j = 0; j < 16; ++j) acc += Pna_sh[m * 16 + j] * s_sh[j * 256 + c];
        #pragma unroll
        for (int q = 0; q < 4; ++q) acc += Pnp_sh[m * 4 + q] * lo_sh[q * 256 + c];
        out[(size_t)tok * SD + m * 256 + c] = acc;
    }
}

extern "C" void kernel_launch(void* const* d_in, const int* in_sizes, int n_in,
                              void* d_out, int out_size, void* d_ws, size_t ws_size,
                              hipStream_t stream)
{
    const float* s        = (const float*)d_in[0];
    const float* gamma    = (const float*)d_in[1];
    const float* compress = (const float*)d_in[2];
    const float* a_pre    = (const float*)d_in[3];
    const float* tl_pre   = (const float*)d_in[4];
    const float* H_pre    = (const float*)d_in[5];
    const float* a_al     = (const float*)d_in[6];
    const float* tl_al    = (const float*)d_in[7];
    const float* H_al     = (const float*)d_in[8];
    const float* a_nx     = (const float*)d_in[9];
    const float* tl_nx    = (const float*)d_in[10];
    const float* H_nx     = (const float*)d_in[11];
    const float* a_po     = (const float*)d_in[12];
    const float* tl_po    = (const float*)d_in[13];
    const float* H_po     = (const float*)d_in[14];
    const float* W        = (const float*)d_in[15];
    float* out = (float*)d_out;

    char* p = (char*)d_ws;
    unsigned short* lo_bf    = (unsigned short*)p; p += (size_t)8192 * 1024 * 2;  // 16.78 MB
    float* Pna               = (float*)p;          p += (size_t)8192 * 256 * 4;   //  8.39 MB
    float* Pnp               = (float*)p;          p += (size_t)8192 * 64 * 4;    //  2.10 MB
    unsigned short* layer_in = (unsigned short*)p; p += (size_t)8192 * 1024 * 2;  // 16.78 MB
    unsigned short* WT       = (unsigned short*)p; p += (size_t)1024 * 1024 * 2;  //  2.10 MB
    unsigned short* cgT      = (unsigned short*)p; p += (size_t)64 * SD * 2;      //  0.52 MB
    unsigned short* tlT      = (unsigned short*)p; p += (size_t)640 * 64 * 2 + 128;
    float* Ppre              = (float*)p;          p += (size_t)8192 * 64 * 4;    //  2.10 MB
    unsigned short* s_bf     = (unsigned short*)p; p += (size_t)NTOK * SD * 2;    // 67.11 MB
    const bool use_sbf = ((size_t)(p - (char*)d_ws) <= ws_size);

    k_preall<<<480, 256, 0, stream>>>(W, WT, compress, gamma, cgT,
                                      tl_pre, tl_al, tl_nx, tl_po, tlT);
    k_front<<<512, 256, 0, stream>>>(s, cgT, tlT,
                                     a_pre, H_pre, a_al, H_al,
                                     a_nx, H_nx, a_po, H_po,
                                     Ppre, Pna, Pnp,
                                     use_sbf ? s_bf : (unsigned short*)nullptr);
    if (use_sbf) {
        k_apply2<true><<<NTOK, 256, 0, stream>>>(s, s_bf, Ppre, layer_in);
    } else {
        k_apply2<false><<<NTOK, 256, 0, stream>>>(s, s_bf, Ppre, layer_in);
    }
    k_gemm_bf16<<<dim3(8, 64), 256, 0, stream>>>(layer_in, WT, lo_bf);
    if (use_sbf) {
        k_final2<true><<<NTOK, 256, 0, stream>>>(s, s_bf, lo_bf, Pna, Pnp, out);
    } else {
        k_final2<false><<<NTOK, 256, 0, stream>>>(s, s_bf, lo_bf, Pna, Pnp, out);
    }
}

// Round 8
// 195.671 us; speedup vs baseline: 1.0961x; 1.0011x over previous
//
#include <hip/hip_runtime.h>
#include <math.h>

#define NTOK 8192
#define SD   4096
#define ITERS 20

typedef __attribute__((ext_vector_type(8))) short short8;
typedef __attribute__((ext_vector_type(8))) unsigned short ushort8;
typedef __attribute__((ext_vector_type(4))) unsigned short us4;
typedef __attribute__((ext_vector_type(4))) float f32x4;

__device__ inline unsigned short f2bf(float x) {
    unsigned int u = __float_as_uint(x);
    unsigned int r = (u + 0x7FFFu + ((u >> 16) & 1u)) >> 16;
    return (unsigned short)r;
}
__device__ inline float bf2f(unsigned short u) {
    return __uint_as_float((unsigned int)u << 16);
}

// ---------------- Kernel PREALL: fused WT + cgT + tlT prep ----------------
__global__ __launch_bounds__(256) void k_preall(const float* __restrict__ W, unsigned short* __restrict__ WT,
                                                const float* __restrict__ compress, const float* __restrict__ gamma,
                                                unsigned short* __restrict__ cgT,
                                                const float* __restrict__ tl_pre, const float* __restrict__ tl_al,
                                                const float* __restrict__ tl_nx,  const float* __restrict__ tl_po,
                                                unsigned short* __restrict__ tlT)
{
    const int b = blockIdx.x;
    const int tid = threadIdx.x;
    if (b < 256) {
        __shared__ float tb[64][65];
        const int k0 = (b >> 4) * 64, n0 = (b & 15) * 64;
        #pragma unroll 4
        for (int q = 0; q < 16; ++q) {
            const int idx = q * 256 + tid;
            const int r = idx >> 6, c = idx & 63;
            tb[r][c] = W[(size_t)(k0 + r) * 1024 + n0 + c];
        }
        __syncthreads();
        #pragma unroll 4
        for (int q = 0; q < 16; ++q) {
            const int idx = q * 256 + tid;
            const int n = idx >> 6, k = idx & 63;
            WT[(size_t)(n0 + n) * 1024 + k0 + k] = f2bf(tb[k][n]);
        }
    } else if (b < 320) {
        __shared__ float tb2[64][65];
        __shared__ float gsh[64];
        const int k0 = (b - 256) * 64;
        #pragma unroll 4
        for (int q = 0; q < 16; ++q) {
            const int idx = q * 256 + tid;
            const int r = idx >> 6, dd = idx & 63;
            tb2[r][dd] = compress[(size_t)(k0 + r) * 64 + dd];
        }
        if (tid < 64) gsh[tid] = gamma[k0 + tid] + 1.0f;
        __syncthreads();
        #pragma unroll 4
        for (int q = 0; q < 16; ++q) {
            const int idx = q * 256 + tid;
            const int d = idx >> 6, r = idx & 63;
            cgT[(size_t)d * SD + k0 + r] = f2bf(tb2[r][d] * gsh[r]);
        }
    } else {
        const int idx = (b - 320) * 256 + tid;
        const int k = idx / 640, n = idx - k * 640;
        float v;
        if (n < 64)       v = tl_pre[k * 64 + n];
        else if (n < 320) v = tl_al[k * 256 + (n - 64)];
        else if (n < 576) v = tl_nx[k * 256 + (n - 320)];
        else              v = tl_po[k * 64 + (n - 576)];
        tlT[(size_t)n * 64 + k] = f2bf(v);
    }
}

// ---------------- Kernel FRONT2: barrier-free code GEMM (direct-global fragments) ----------------
//                  -> logits (MFMA, LDS) -> 4 linear Sinkhorns -> compose
// 512 blocks x 16 tokens, 256 threads.
#define LGS 660   // lg_sh row stride (ushorts): 1320 B -> bank offset 10 -> conflict-free-ish
__global__ __launch_bounds__(256) void k_front2(const float* __restrict__ s,
                                                const unsigned short* __restrict__ cgT,
                                                const unsigned short* __restrict__ tlT,
                                                const float* __restrict__ a_pre_p, const float* __restrict__ H_pre,
                                                const float* __restrict__ a_al_p,  const float* __restrict__ H_al,
                                                const float* __restrict__ a_nx_p,  const float* __restrict__ H_nx,
                                                const float* __restrict__ a_po_p,  const float* __restrict__ H_po,
                                                float* __restrict__ Ppre,
                                                float* __restrict__ Pna, float* __restrict__ Pnp)
{
    // LDS layout (phased aliasing):
    //  [0,2304)        code_sh   us[16*72]        (phaseB -> phaseC)
    //  [2304,23424)    regionA:  red f32[4*16*68] (phaseB)  |  lg_sh us[16*LGS] (phaseC -> phaseD)
    //  [23424,40064)   Pal f32[16*260]            (phaseD -> phaseE)
    //  [40064,56704)   Pnx f32[16*260]
    //  [56704,61056)   Ppo f32[16*68]
    //  [61056,61312)   ssq_part f32[4*16]
    //  [61312,61376)   ssq_sh f32[16]
    __shared__ __align__(16) char smem[61440];
    unsigned short* code_sh  = (unsigned short*)(smem);
    float*          red      = (float*)(smem + 2304);
    unsigned short* lg_sh    = (unsigned short*)(smem + 2304);
    float*          Pal_sh   = (float*)(smem + 23424);
    float*          Pnx_sh   = (float*)(smem + 40064);
    float*          Ppo_sh   = (float*)(smem + 56704);
    float*          ssq_part = (float*)(smem + 61056);
    float*          ssq_sh   = (float*)(smem + 61312);

    const int tid  = threadIdx.x;
    const int lane = tid & 63;
    const int wid  = tid >> 6;
    const int tok0 = blockIdx.x * 16;
    const int row  = lane & 15;
    const int kq   = lane >> 4;
    const int wk   = wid * 32;

    // ---- phase A: code partials, zero barriers, fragments direct from global ----
    float ssq = 0.f;
    f32x4 acc[4];
    #pragma unroll
    for (int ni = 0; ni < 4; ++ni) acc[ni] = (f32x4){0.f, 0.f, 0.f, 0.f};

    const float*          srow  = s   + (size_t)(tok0 + row) * SD + wk + kq * 8;
    const unsigned short* cgrow = cgT + wk + kq * 8;

    #pragma unroll 2
    for (int ks = 0; ks < 32; ++ks) {
        const int kg = ks * 128;
        float4 v0 = *(const float4*)(srow + kg);
        float4 v1 = *(const float4*)(srow + kg + 4);
        ssq += v0.x*v0.x + v0.y*v0.y + v0.z*v0.z + v0.w*v0.w
             + v1.x*v1.x + v1.y*v1.y + v1.z*v1.z + v1.w*v1.w;
        short8 a;
        a[0]=(short)f2bf(v0.x); a[1]=(short)f2bf(v0.y); a[2]=(short)f2bf(v0.z); a[3]=(short)f2bf(v0.w);
        a[4]=(short)f2bf(v1.x); a[5]=(short)f2bf(v1.y); a[6]=(short)f2bf(v1.z); a[7]=(short)f2bf(v1.w);
        short8 b[4];
        #pragma unroll
        for (int ni = 0; ni < 4; ++ni)
            b[ni] = *(const short8*)(cgrow + (size_t)(ni * 16 + row) * SD + kg);
        #pragma unroll
        for (int ni = 0; ni < 4; ++ni)
            acc[ni] = __builtin_amdgcn_mfma_f32_16x16x32_bf16(a, b[ni], acc[ni], 0, 0, 0);
    }

    // ssq: sum across the 4 kq groups (lanes row, row+16, row+32, row+48)
    ssq += __shfl_xor(ssq, 16);
    ssq += __shfl_xor(ssq, 32);
    if (lane < 16) ssq_part[wid * 16 + row] = ssq;

    // ---- phase B: per-wave partials -> reduce -> code_sh (bf16) ----
    #pragma unroll
    for (int ni = 0; ni < 4; ++ni)
        #pragma unroll
        for (int r = 0; r < 4; ++r)
            red[wid * 1088 + ((lane >> 4) * 4 + r) * 68 + ni * 16 + (lane & 15)] = acc[ni][r];
    __syncthreads();
    if (tid < 16) {
        float t = ssq_part[tid] + ssq_part[16 + tid] + ssq_part[32 + tid] + ssq_part[48 + tid];
        ssq_sh[tid] = 64.0f / fmaxf(sqrtf(t), 1e-12f);
    }
    __syncthreads();
    #pragma unroll
    for (int q = 0; q < 4; ++q) {
        const int idx = q * 256 + tid;
        const int tok = idx >> 6, d = idx & 63;
        float v = red[0 * 1088 + tok * 68 + d] + red[1 * 1088 + tok * 68 + d]
                + red[2 * 1088 + tok * 68 + d] + red[3 * 1088 + tok * 68 + d];
        code_sh[tok * 72 + d] = f2bf(v * ssq_sh[tok]);
    }
    __syncthreads();  // code_sh ready; red dead -> lg_sh may be written

    // ---- phase C: logits[16][640] = code @ tlcat^T (MFMA), bf16 into lg_sh ----
    {
        f32x4 acc2[10];
        #pragma unroll
        for (int ni = 0; ni < 10; ++ni) acc2[ni] = (f32x4){0.f, 0.f, 0.f, 0.f};
        const int nbase = wid * 160;
        #pragma unroll
        for (int ks = 0; ks < 2; ++ks) {
            const int ko = ks * 32 + (lane >> 4) * 8;
            short8 a = *(const short8*)(code_sh + (lane & 15) * 72 + ko);
            #pragma unroll
            for (int ni = 0; ni < 10; ++ni) {
                short8 b = *(const short8*)(tlT + (size_t)(nbase + ni * 16 + (lane & 15)) * 64 + ko);
                acc2[ni] = __builtin_amdgcn_mfma_f32_16x16x32_bf16(a, b, acc2[ni], 0, 0, 0);
            }
        }
        #pragma unroll
        for (int ni = 0; ni < 10; ++ni)
            #pragma unroll
            for (int r = 0; r < 4; ++r)
                lg_sh[((lane >> 4) * 4 + r) * LGS + nbase + ni * 16 + (lane & 15)] = f2bf(acc2[ni][r]);
    }
    __syncthreads();

    // ---- phase D: linear Sinkhorns (4 lanes per token) ----
    const int t_in = lane >> 2;
    const int sub  = lane & 3;
    const int tok  = tok0 + t_in;

    if (wid < 2) {
        const float alpha = (wid == 0) ? (*a_al_p) : (*a_nx_p);
        const float* Hp   = ((wid == 0) ? H_al : H_nx) + sub * 64;
        const unsigned short* lgp = lg_sh + t_in * LGS + (wid == 0 ? 64 : 320) + sub * 64;
        float Km[4][16];
        #pragma unroll
        for (int rr = 0; rr < 4; ++rr)
            #pragma unroll
            for (int h = 0; h < 2; ++h) {
                ushort8 rv = *(const ushort8*)(lgp + rr * 16 + h * 8);
                float4 h0 = *(const float4*)(Hp + rr * 16 + h * 8);
                float4 h1 = *(const float4*)(Hp + rr * 16 + h * 8 + 4);
                Km[rr][h*8+0] = expf(alpha * bf2f(rv[0]) + h0.x);
                Km[rr][h*8+1] = expf(alpha * bf2f(rv[1]) + h0.y);
                Km[rr][h*8+2] = expf(alpha * bf2f(rv[2]) + h0.z);
                Km[rr][h*8+3] = expf(alpha * bf2f(rv[3]) + h0.w);
                Km[rr][h*8+4] = expf(alpha * bf2f(rv[4]) + h1.x);
                Km[rr][h*8+5] = expf(alpha * bf2f(rv[5]) + h1.y);
                Km[rr][h*8+6] = expf(alpha * bf2f(rv[6]) + h1.z);
                Km[rr][h*8+7] = expf(alpha * bf2f(rv[7]) + h1.w);
            }
        float v[16], u[4];
        #pragma unroll
        for (int c = 0; c < 16; ++c) v[c] = 1.0f;
        for (int it = 0; it < ITERS; ++it) {
            #pragma unroll
            for (int rr = 0; rr < 4; ++rr) {
                float su = 0.f;
                #pragma unroll
                for (int c = 0; c < 16; ++c) su += Km[rr][c] * v[c];
                u[rr] = 0.0625f * __builtin_amdgcn_rcpf(su);
            }
            float pv[16];
            #pragma unroll
            for (int c = 0; c < 16; ++c)
                pv[c] = Km[0][c]*u[0] + Km[1][c]*u[1] + Km[2][c]*u[2] + Km[3][c]*u[3];
            #pragma unroll
            for (int c = 0; c < 16; ++c) pv[c] += __shfl_xor(pv[c], 1);
            #pragma unroll
            for (int c = 0; c < 16; ++c) pv[c] += __shfl_xor(pv[c], 2);
            #pragma unroll
            for (int c = 0; c < 16; ++c) v[c] = 0.0625f * __builtin_amdgcn_rcpf(pv[c]);
        }
        float* dst = ((wid == 0) ? Pal_sh : Pnx_sh) + t_in * 260;
        #pragma unroll
        for (int rr = 0; rr < 4; ++rr) {
            const float su16 = 16.0f * u[rr];
            #pragma unroll
            for (int c = 0; c < 16; ++c)
                dst[(sub * 4 + rr) * 16 + c] = Km[rr][c] * su16 * v[c];
        }
    } else if (wid == 2) {
        const float alpha = *a_pre_p;
        const unsigned short* lgp = lg_sh + t_in * LGS + sub * 16;
        const float* Hp  = H_pre + sub * 16;
        float Km[16];
        #pragma unroll
        for (int h = 0; h < 2; ++h) {
            ushort8 rv = *(const ushort8*)(lgp + h * 8);
            float4 h0 = *(const float4*)(Hp + h * 8);
            float4 h1 = *(const float4*)(Hp + h * 8 + 4);
            Km[h*8+0] = expf(alpha * bf2f(rv[0]) + h0.x);
            Km[h*8+1] = expf(alpha * bf2f(rv[1]) + h0.y);
            Km[h*8+2] = expf(alpha * bf2f(rv[2]) + h0.z);
            Km[h*8+3] = expf(alpha * bf2f(rv[3]) + h0.w);
            Km[h*8+4] = expf(alpha * bf2f(rv[4]) + h1.x);
            Km[h*8+5] = expf(alpha * bf2f(rv[5]) + h1.y);
            Km[h*8+6] = expf(alpha * bf2f(rv[6]) + h1.z);
            Km[h*8+7] = expf(alpha * bf2f(rv[7]) + h1.w);
        }
        float v[16], u;
        #pragma unroll
        for (int c = 0; c < 16; ++c) v[c] = 1.0f;
        for (int it = 0; it < ITERS; ++it) {
            float su = 0.f;
            #pragma unroll
            for (int c = 0; c < 16; ++c) su += Km[c] * v[c];
            u = 0.25f * __builtin_amdgcn_rcpf(su);
            float pv[16];
            #pragma unroll
            for (int c = 0; c < 16; ++c) pv[c] = Km[c] * u;
            #pragma unroll
            for (int c = 0; c < 16; ++c) pv[c] += __shfl_xor(pv[c], 1);
            #pragma unroll
            for (int c = 0; c < 16; ++c) pv[c] += __shfl_xor(pv[c], 2);
            #pragma unroll
            for (int c = 0; c < 16; ++c) v[c] = 0.0625f * __builtin_amdgcn_rcpf(pv[c]);
        }
        const float su4 = 4.0f * u;
        #pragma unroll
        for (int c = 0; c < 16; ++c)
            Ppre[(size_t)tok * 64 + sub * 16 + c] = Km[c] * su4 * v[c];
    } else {
        const float alpha = *a_po_p;
        const unsigned short* lgp = lg_sh + t_in * LGS + 576 + sub * 16;
        const float* Hp  = H_po + sub * 16;
        float Km[4][4];
        #pragma unroll
        for (int rr = 0; rr < 4; ++rr) {
            us4 rv = *(const us4*)(lgp + rr * 4);
            float4 hv = *(const float4*)(Hp + rr * 4);
            Km[rr][0] = expf(alpha * bf2f(rv[0]) + hv.x);
            Km[rr][1] = expf(alpha * bf2f(rv[1]) + hv.y);
            Km[rr][2] = expf(alpha * bf2f(rv[2]) + hv.z);
            Km[rr][3] = expf(alpha * bf2f(rv[3]) + hv.w);
        }
        float v[4], u[4];
        #pragma unroll
        for (int c = 0; c < 4; ++c) v[c] = 1.0f;
        for (int it = 0; it < ITERS; ++it) {
            #pragma unroll
            for (int rr = 0; rr < 4; ++rr) {
                float su = 0.f;
                #pragma unroll
                for (int c = 0; c < 4; ++c) su += Km[rr][c] * v[c];
                u[rr] = 0.0625f * __builtin_amdgcn_rcpf(su);
            }
            float pv[4];
            #pragma unroll
            for (int c = 0; c < 4; ++c)
                pv[c] = Km[0][c]*u[0] + Km[1][c]*u[1] + Km[2][c]*u[2] + Km[3][c]*u[3];
            #pragma unroll
            for (int c = 0; c < 4; ++c) pv[c] += __shfl_xor(pv[c], 1);
            #pragma unroll
            for (int c = 0; c < 4; ++c) pv[c] += __shfl_xor(pv[c], 2);
            #pragma unroll
            for (int c = 0; c < 4; ++c) v[c] = 0.25f * __builtin_amdgcn_rcpf(pv[c]);
        }
        #pragma unroll
        for (int rr = 0; rr < 4; ++rr) {
            const float su16 = 16.0f * u[rr];
            #pragma unroll
            for (int c = 0; c < 4; ++c)
                Ppo_sh[t_in * 68 + (sub * 4 + rr) * 4 + c] = Km[rr][c] * su16 * v[c];
        }
    }
    __syncthreads();

    // ---- phase E: compose Pna = Pnx@Pal, Pnp = Pnx@Ppo ----
    const int ct = tid >> 4;
    const int cj = tid & 15;
    const float* pnx = Pnx_sh + ct * 260;
    const float* pal = Pal_sh + ct * 260;
    const float* ppo = Ppo_sh + ct * 68;
    #pragma unroll
    for (int m = 0; m < 16; ++m) {
        float a2 = 0.f;
        #pragma unroll
        for (int t2 = 0; t2 < 16; ++t2) a2 += pnx[m * 16 + t2] * pal[t2 * 16 + cj];
        Pna[(size_t)(tok0 + ct) * 256 + m * 16 + cj] = a2;
    }
    #pragma unroll
    for (int e = 0; e < 4; ++e) {
        const int idx = cj * 4 + e;
        const int m = idx >> 2, q = idx & 3;
        float a2 = 0.f;
        #pragma unroll
        for (int t2 = 0; t2 < 16; ++t2) a2 += pnx[m * 16 + t2] * ppo[t2 * 4 + q];
        Pnp[(size_t)(tok0 + ct) * 64 + idx] = a2;
    }
}

// ---------------- Kernel AP: layer_in = Ppre @ s ----------------
__global__ __launch_bounds__(256) void k_apply(const float* __restrict__ s,
                                               const float* __restrict__ Ppre,
                                               unsigned short* __restrict__ layer_in)
{
    __shared__ float s_sh[SD];
    __shared__ float P_sh[64];
    const int tid = threadIdx.x;
    const int tok = blockIdx.x;

    {
        const float4* sp4 = (const float4*)(s + (size_t)tok * SD);
        #pragma unroll
        for (int j = 0; j < 4; ++j)
            *(float4*)(s_sh + j * 1024 + tid * 4) = sp4[j * 256 + tid];
    }
    if (tid < 64) P_sh[tid] = Ppre[(size_t)tok * 64 + tid];
    __syncthreads();

    #pragma unroll
    for (int i = 0; i < 4; ++i) {
        float acc = 0.f;
        #pragma unroll
        for (int j = 0; j < 16; ++j) acc += P_sh[i * 16 + j] * s_sh[j * 256 + tid];
        layer_in[(size_t)tok * 1024 + i * 256 + tid] = f2bf(acc);
    }
}

// ---------------- Kernel C: layer_out(bf16) = layer_in @ WT^T via MFMA ----------------
__global__ __launch_bounds__(256) void k_gemm_bf16(const unsigned short* __restrict__ A,
                                                   const unsigned short* __restrict__ BT,
                                                   unsigned short* __restrict__ Cb)
{
    __shared__ unsigned short Abuf[128 * 48];
    __shared__ unsigned short Bbuf[128 * 48];
    const int tid  = threadIdx.x;
    const int lane = tid & 63;
    const int wid  = tid >> 6;
    const int wr   = wid >> 1, wc = wid & 1;
    const int m0 = blockIdx.y * 128, n0 = blockIdx.x * 128;

    f32x4 acc[4][4];
    #pragma unroll
    for (int mi = 0; mi < 4; ++mi)
        #pragma unroll
        for (int ni = 0; ni < 4; ++ni) acc[mi][ni] = (f32x4){0.f, 0.f, 0.f, 0.f};

    for (int k0 = 0; k0 < 1024; k0 += 32) {
        __syncthreads();
        #pragma unroll
        for (int h = 0; h < 2; ++h) {
            const int idx = h * 256 + tid;
            const int row = idx >> 2, kq = idx & 3;
            float4 av = *(const float4*)(A + (size_t)(m0 + row) * 1024 + k0 + kq * 8);
            *(float4*)(Abuf + row * 48 + kq * 8) = av;
            float4 bv = *(const float4*)(BT + (size_t)(n0 + row) * 1024 + k0 + kq * 8);
            *(float4*)(Bbuf + row * 48 + kq * 8) = bv;
        }
        __syncthreads();

        short8 a[4], b[4];
        #pragma unroll
        for (int mi = 0; mi < 4; ++mi)
            a[mi] = *(const short8*)(Abuf + (wr * 64 + mi * 16 + (lane & 15)) * 48 + (lane >> 4) * 8);
        #pragma unroll
        for (int ni = 0; ni < 4; ++ni)
            b[ni] = *(const short8*)(Bbuf + (wc * 64 + ni * 16 + (lane & 15)) * 48 + (lane >> 4) * 8);
        #pragma unroll
        for (int mi = 0; mi < 4; ++mi)
            #pragma unroll
            for (int ni = 0; ni < 4; ++ni)
                acc[mi][ni] = __builtin_amdgcn_mfma_f32_16x16x32_bf16(a[mi], b[ni], acc[mi][ni], 0, 0, 0);
    }

    #pragma unroll
    for (int mi = 0; mi < 4; ++mi)
        #pragma unroll
        for (int ni = 0; ni < 4; ++ni)
            #pragma unroll
            for (int r = 0; r < 4; ++r)
                Cb[(size_t)(m0 + wr * 64 + mi * 16 + (lane >> 4) * 4 + r) * 1024 +
                   n0 + wc * 64 + ni * 16 + (lane & 15)] = f2bf(acc[mi][ni][r]);
}

// ---------------- Kernel D: s_next = P_na @ s + P_np @ layer_out ----------------
__global__ __launch_bounds__(256) void k_final(const float* __restrict__ s,
                                               const unsigned short* __restrict__ lo_bf,
                                               const float* __restrict__ Pna,
                                               const float* __restrict__ Pnp,
                                               float* __restrict__ out)
{
    __shared__ float s_sh[SD];
    __shared__ float lo_sh[1024];
    __shared__ float Pna_sh[256];
    __shared__ float Pnp_sh[64];
    const int tid = threadIdx.x;
    const int tok = blockIdx.x;

    {
        const float4* sp4 = (const float4*)(s + (size_t)tok * SD);
        #pragma unroll
        for (int j = 0; j < 4; ++j)
            *(float4*)(s_sh + j * 1024 + tid * 4) = sp4[j * 256 + tid];
    }
    {
        us4 lv = *(const us4*)(lo_bf + (size_t)tok * 1024 + tid * 4);
        float4 f;
        f.x = bf2f(lv[0]); f.y = bf2f(lv[1]); f.z = bf2f(lv[2]); f.w = bf2f(lv[3]);
        *(float4*)(lo_sh + tid * 4) = f;
    }
    Pna_sh[tid] = Pna[(size_t)tok * 256 + tid];
    if (tid < 64) Pnp_sh[tid] = Pnp[(size_t)tok * 64 + tid];
    __syncthreads();

    const int c = tid;
    #pragma unroll
    for (int m = 0; m < 16; ++m) {
        float acc = 0.f;
        #pragma unroll
        for (int j = 0; j < 16; ++j) acc += Pna_sh[m * 16 + j] * s_sh[j * 256 + c];
        #pragma unroll
        for (int q = 0; q < 4; ++q) acc += Pnp_sh[m * 4 + q] * lo_sh[q * 256 + c];
        out[(size_t)tok * SD + m * 256 + c] = acc;
    }
}

extern "C" void kernel_launch(void* const* d_in, const int* in_sizes, int n_in,
                              void* d_out, int out_size, void* d_ws, size_t ws_size,
                              hipStream_t stream)
{
    const float* s        = (const float*)d_in[0];
    const float* gamma    = (const float*)d_in[1];
    const float* compress = (const float*)d_in[2];
    const float* a_pre    = (const float*)d_in[3];
    const float* tl_pre   = (const float*)d_in[4];
    const float* H_pre    = (const float*)d_in[5];
    const float* a_al     = (const float*)d_in[6];
    const float* tl_al    = (const float*)d_in[7];
    const float* H_al     = (const float*)d_in[8];
    const float* a_nx     = (const float*)d_in[9];
    const float* tl_nx    = (const float*)d_in[10];
    const float* H_nx     = (const float*)d_in[11];
    const float* a_po     = (const float*)d_in[12];
    const float* tl_po    = (const float*)d_in[13];
    const float* H_po     = (const float*)d_in[14];
    const float* W        = (const float*)d_in[15];
    float* out = (float*)d_out;

    char* p = (char*)d_ws;
    unsigned short* lo_bf    = (unsigned short*)p; p += (size_t)8192 * 1024 * 2;
    float* Pna               = (float*)p;          p += (size_t)8192 * 256 * 4;
    float* Pnp               = (float*)p;          p += (size_t)8192 * 64 * 4;
    unsigned short* layer_in = (unsigned short*)p; p += (size_t)8192 * 1024 * 2;
    unsigned short* WT       = (unsigned short*)p; p += (size_t)1024 * 1024 * 2;
    unsigned short* cgT      = (unsigned short*)p; p += (size_t)64 * SD * 2;
    unsigned short* tlT      = (unsigned short*)p; p += (size_t)640 * 64 * 2 + 128;
    float* Ppre              = (float*)p;          p += (size_t)8192 * 64 * 4;

    k_preall<<<480, 256, 0, stream>>>(W, WT, compress, gamma, cgT,
                                      tl_pre, tl_al, tl_nx, tl_po, tlT);
    k_front2<<<512, 256, 0, stream>>>(s, cgT, tlT,
                                      a_pre, H_pre, a_al, H_al,
                                      a_nx, H_nx, a_po, H_po,
                                      Ppre, Pna, Pnp);
    k_apply<<<NTOK, 256, 0, stream>>>(s, Ppre, layer_in);
    k_gemm_bf16<<<dim3(8, 64), 256, 0, stream>>>(layer_in, WT, lo_bf);
    k_final<<<NTOK, 256, 0, stream>>>(s, lo_bf, Pna, Pnp, out);
}